// Round 18
// baseline (49.855 us; speedup 1.0000x reference)
//
#include <hip/hip_runtime.h>
#include <math.h>

#define KS    31
#define KSP   32           // padded taps per row (col/row 31: env=0)
#define PADV  15
#define IMG   320
#define NOUT  289          // valid centered outputs (i in [15, 304))
#define NTH   180
#define TABQ  (KSP * KSP)  // 1024 float2 per theta (8 KB slab)
#define RBLK  128          // reduction blocks

// conv block geometry: 8 pixels (4 wide x 2 high), one pixel per 32-lane half
#define PBX   4
#define PBY   2
#define TROWS (PBY + KS)        // 33
#define TSTR  37                // ODD LDS row stride (conflict-free, measured r10)
#define NSTG  (TROWS * TSTR)    // 1221

typedef float f32x4 __attribute__((ext_vector_type(4)));

// ---- per-theta (env, phi) table: w(t,f,tap) = env * cos_rev(f0 * phi) ----
__global__ __launch_bounds__(256) void build_eftab(float2* __restrict__ tab) {
    const int t = blockIdx.x >> 2;
    const int e = (blockIdx.x & 3) * 256 + threadIdx.x;
    const float th = ((float)t / 180.0f) * 3.14159265358979323846f;
    float st, ct;
    sincosf(th, &st, &ct);
    int dy = e >> 5, dx = e & 31;
    float2 v = make_float2(0.0f, 0.0f);
    if (dy < KS && dx < KS) {
        float y = (float)(dy - PADV);
        float x = (float)(dx - PADV);
        float x_t = fmaf(x,  ct, y * st);
        float y_t = fmaf(-x, st, y * ct);
        float gamma = fmaf(0.04f, fabsf(y_t), 1.0f);      // 1 + 0.6|y_t|/15
        float gyt = gamma * y_t;
        float env = expf(-fmaf(x_t, x_t, gyt * gyt) * (1.0f / 72.0f));
        float phi = fmaf(x_t * y_t, (1.0f / 45.0f), x_t); // f_local*x_t = f0*phi
        v = make_float2(env, phi);
    }
    tab[(size_t)t * TABQ + e] = v;
}

// 256 threads = 4 waves = 8 pixels; half-wave per pixel. ALL 16 slab loads
// issued in one burst, then counted-vmcnt WAITTIE(12/8/4/0) per group
// (tied "+v" operands pin post-wait values — r14-proven discipline).
__global__ __launch_bounds__(256, 2) void gabor_conv(
    const float* __restrict__ fp, const int* __restrict__ fmap,
    const int* __restrict__ tmap, const float2* __restrict__ tab,
    float* __restrict__ out)
{
    __shared__ float tile[NSTG];
    const int bh = blockIdx.y * PBY;
    const int bw = blockIdx.x * PBX;
    const int tid = threadIdx.x;

    for (int i = tid; i < NSTG; i += 256) {
        int r = i / TSTR, c = i - r * TSTR;
        int gr = bh + r, gc = bw + c;
        tile[i] = (gr < IMG && gc < IMG) ? fp[gr * IMG + gc] : 0.0f;
    }
    __syncthreads();

    const int wave = tid >> 6, lane = tid & 63;
    const int half = lane >> 5, l = lane & 31;
    const int lr = l & 15, lh = l >> 4;          // col-slot / row-parity
    const int pb  = wave * 2 + half;             // pixel 0..7 within block
    const int pxl = pb & 3, pyl = pb >> 2;
    const int oy = bh + pyl, ox = bw + pxl;
    const bool valid = (oy < NOUT) && (ox < NOUT);

    float acc0 = 0.0f, acc1 = 0.0f;
    if (valid) {
        const int iy = oy + PADV, ix = ox + PADV;
        const int theta = tmap[iy * IMG + ix];
        float f0 = 0.025f + 0.0015f * (float)fmap[iy * IMG + ix];
        asm volatile("" : "+v"(f0));             // force fmap load before pipeline

        // lane l, float4 index k = 32*i + l -> byte 512*i + 16*l
        unsigned long long a  =
            (unsigned long long)(tab + (size_t)theta * TABQ) + (size_t)l * 16;
        unsigned long long a2 = a + 4096;
        const float* tbase = &tile[(pyl + lh) * TSTR + pxl + 2 * lr];

        f32x4 g0a, g0b, g0c, g0d, g1a, g1b, g1c, g1d;
        f32x4 g2a, g2b, g2c, g2d, g3a, g3b, g3c, g3d;

#define ISSUE(R0,R1,R2,R3,A,O0,O1,O2,O3) asm volatile(                        \
        "global_load_dwordx4 %0, %4, off offset:" #O0 "\n\t"                  \
        "global_load_dwordx4 %1, %4, off offset:" #O1 "\n\t"                  \
        "global_load_dwordx4 %2, %4, off offset:" #O2 "\n\t"                  \
        "global_load_dwordx4 %3, %4, off offset:" #O3                         \
        : "=&v"(R0), "=&v"(R1), "=&v"(R2), "=&v"(R3) : "v"(A) : "memory")
#define WAITTIE(N,R0,R1,R2,R3)                                                \
        asm volatile("s_waitcnt vmcnt(" #N ")"                                \
            : "+v"(R0), "+v"(R1), "+v"(R2), "+v"(R3) :: "memory");            \
        __builtin_amdgcn_sched_barrier(0)
#define COMP(W, i) { const float* tr_ = tbase + 2 * (i) * TSTR;               \
        float w0_ = W.x * __builtin_amdgcn_cosf(f0 * W.y);                    \
        float w1_ = W.z * __builtin_amdgcn_cosf(f0 * W.w);                    \
        acc0 = fmaf(tr_[0], w0_, acc0); acc1 = fmaf(tr_[1], w1_, acc1); }

        ISSUE(g0a,g0b,g0c,g0d, a,  0,    512,  1024, 1536);
        ISSUE(g1a,g1b,g1c,g1d, a,  2048, 2560, 3072, 3584);
        ISSUE(g2a,g2b,g2c,g2d, a2, 0,    512,  1024, 1536);
        ISSUE(g3a,g3b,g3c,g3d, a2, 2048, 2560, 3072, 3584);
        WAITTIE(12, g0a,g0b,g0c,g0d);                // G0 ready (12 in flight)
        COMP(g0a, 0) COMP(g0b, 1) COMP(g0c, 2) COMP(g0d, 3)
        __builtin_amdgcn_sched_barrier(0);
        WAITTIE(8, g1a,g1b,g1c,g1d);                 // G1 ready
        COMP(g1a, 4) COMP(g1b, 5) COMP(g1c, 6) COMP(g1d, 7)
        __builtin_amdgcn_sched_barrier(0);
        WAITTIE(4, g2a,g2b,g2c,g2d);                 // G2 ready
        COMP(g2a, 8) COMP(g2b, 9) COMP(g2c, 10) COMP(g2d, 11)
        __builtin_amdgcn_sched_barrier(0);
        WAITTIE(0, g3a,g3b,g3c,g3d);                 // G3 ready
        COMP(g3a, 12) COMP(g3b, 13) COMP(g3c, 14) COMP(g3d, 15)
#undef COMP
#undef WAITTIE
#undef ISSUE
    }

    // reduce the 32 lanes of each half-wave
    float v = acc0 + acc1;
    v += __shfl_xor(v, 1, 64);
    v += __shfl_xor(v, 2, 64);
    v += __shfl_xor(v, 4, 64);
    v += __shfl_xor(v, 8, 64);
    v += __shfl_xor(v, 16, 64);

    if (valid && l == 0)
        out[(oy + PADV) * IMG + (ox + PADV)] = v;
}

// ---- stage 1: min/max over full image (inner from out, border from fp) ----
__global__ __launch_bounds__(256) void reduce_partials(
    const float* __restrict__ fp, const float* __restrict__ out,
    float2* __restrict__ part)
{
    __shared__ float smin[4], smax[4];
    float vmin = INFINITY, vmax = -INFINITY;
    for (int p = blockIdx.x * 256 + threadIdx.x; p < IMG * IMG; p += RBLK * 256) {
        int i = p / IMG, j = p - i * IMG;
        bool inner = (i >= PADV) && (i < PADV + NOUT) && (j >= PADV) && (j < PADV + NOUT);
        float v = inner ? out[p] : fp[p];
        vmin = fminf(vmin, v);
        vmax = fmaxf(vmax, v);
    }
    for (int off = 32; off; off >>= 1) {
        vmin = fminf(vmin, __shfl_down(vmin, off, 64));
        vmax = fmaxf(vmax, __shfl_down(vmax, off, 64));
    }
    const int wave = threadIdx.x >> 6;
    if ((threadIdx.x & 63) == 0) { smin[wave] = vmin; smax[wave] = vmax; }
    __syncthreads();
    if (threadIdx.x == 0) {
        vmin = fminf(fminf(smin[0], smin[1]), fminf(smin[2], smin[3]));
        vmax = fmaxf(fmaxf(smax[0], smax[1]), fmaxf(smax[2], smax[3]));
        part[blockIdx.x] = make_float2(vmin, vmax);
    }
}

// ---- stage 2: single block reduces RBLK partials -> mm (plain floats) ----
__global__ __launch_bounds__(RBLK) void reduce_final(
    const float2* __restrict__ part, float* __restrict__ mm)
{
    __shared__ float smin[2], smax[2];
    float2 v = part[threadIdx.x];
    float vmin = v.x, vmax = v.y;
    for (int off = 32; off; off >>= 1) {
        vmin = fminf(vmin, __shfl_down(vmin, off, 64));
        vmax = fmaxf(vmax, __shfl_down(vmax, off, 64));
    }
    const int wave = threadIdx.x >> 6;
    if ((threadIdx.x & 63) == 0) { smin[wave] = vmin; smax[wave] = vmax; }
    __syncthreads();
    if (threadIdx.x == 0) {
        mm[0] = fminf(smin[0], smin[1]);
        mm[1] = fmaxf(smax[0], smax[1]);
    }
}

// ---- finalize: normalize + threshold (border read from fp directly) ----
__global__ __launch_bounds__(256) void finalize(
    const float* __restrict__ fp, float* __restrict__ out,
    const float* __restrict__ mm)
{
    int p = blockIdx.x * 256 + threadIdx.x;
    if (p >= IMG * IMG) return;
    int i = p / IMG, j = p - i * IMG;
    bool inner = (i >= PADV) && (i < PADV + NOUT) && (j >= PADV) && (j < PADV + NOUT);
    float raw = inner ? out[p] : fp[p];
    float mn = mm[0];
    float mx = mm[1] - mn;               // max(out - min) == max0 - min0
    float v  = raw - mn;
    if (mx != 0.0f) v = v / mx * 100.0f;
    out[p] = (v > 55.0f) ? 100.0f : 0.0f;
}

extern "C" void kernel_launch(void* const* d_in, const int* in_sizes, int n_in,
                              void* d_out, int out_size, void* d_ws, size_t ws_size,
                              hipStream_t stream) {
    const float* fp   = (const float*)d_in[0];
    const int*   fmap = (const int*)d_in[1];
    const int*   tmap = (const int*)d_in[2];
    float* out = (float*)d_out;

    float*  mm   = (float*)d_ws;                          // 2 floats
    float2* part = (float2*)((char*)d_ws + 256);          // RBLK float2
    float2* tab  = (float2*)((char*)d_ws + 4096);         // 180*1024*8 = 1.47 MB

    hipLaunchKernelGGL(build_eftab, dim3(NTH * 4), dim3(256), 0, stream, tab);

    dim3 g((NOUT + PBX - 1) / PBX, (NOUT + PBY - 1) / PBY);   // 73 x 145
    hipLaunchKernelGGL(gabor_conv, g, dim3(256), 0, stream, fp, fmap, tmap, tab, out);

    hipLaunchKernelGGL(reduce_partials, dim3(RBLK), dim3(256), 0, stream, fp, out, part);
    hipLaunchKernelGGL(reduce_final,    dim3(1),    dim3(RBLK), 0, stream, part, mm);

    int nblk = (IMG * IMG + 255) / 256;
    hipLaunchKernelGGL(finalize, dim3(nblk), dim3(256), 0, stream, fp, out, mm);
}

// Round 19
// 44.681 us; speedup vs baseline: 1.1158x; 1.1158x over previous
//
#include <hip/hip_runtime.h>
#include <math.h>

#define KS    31
#define KSP   32           // padded taps per row (col/row 31: env=0)
#define PADV  15
#define IMG   320
#define NOUT  289          // valid centered outputs (i in [15, 304))
#define NTH   180
#define TABQ  (KSP * KSP)  // 1024 float2 per theta (8 KB slab)
#define RBLK  128          // reduction blocks

// conv block geometry: 8 pixels (4 wide x 2 high), one pixel per 32-lane half
#define PBX   4
#define PBY   2
#define TROWS (PBY + KS)        // 33
#define TSTR  37                // ODD LDS row stride (conflict-free, measured r10)
#define NSTG  (TROWS * TSTR)    // 1221

typedef float f32x4 __attribute__((ext_vector_type(4)));

// ---- per-theta (env, phi) table: w(t,f,tap) = env * cos_rev(f0 * phi) ----
__global__ __launch_bounds__(256) void build_eftab(float2* __restrict__ tab) {
    const int t = blockIdx.x >> 2;
    const int e = (blockIdx.x & 3) * 256 + threadIdx.x;
    const float th = ((float)t / 180.0f) * 3.14159265358979323846f;
    float st, ct;
    sincosf(th, &st, &ct);
    int dy = e >> 5, dx = e & 31;
    float2 v = make_float2(0.0f, 0.0f);
    if (dy < KS && dx < KS) {
        float y = (float)(dy - PADV);
        float x = (float)(dx - PADV);
        float x_t = fmaf(x,  ct, y * st);
        float y_t = fmaf(-x, st, y * ct);
        float gamma = fmaf(0.04f, fabsf(y_t), 1.0f);      // 1 + 0.6|y_t|/15
        float gyt = gamma * y_t;
        float env = expf(-fmaf(x_t, x_t, gyt * gyt) * (1.0f / 72.0f));
        float phi = fmaf(x_t * y_t, (1.0f / 45.0f), x_t); // f_local*x_t = f0*phi
        v = make_float2(env, phi);
    }
    tab[(size_t)t * TABQ + e] = v;
}

// 256 threads = 4 waves = 8 pixels; half-wave per pixel. Interleaved
// ISSUE/WAITTIE ping-pong (r14-proven): issue G0,G1 -> wait G0 -> issue G2
// -> comp G0 -> wait G1 -> issue G3 -> comp G1 -> wait G2 -> comp G2 ->
// wait G3 -> comp G3. WAITTIE ties "+v" operands so consumers read
// post-wait SSA values (the correctness key discovered in r12-r14).
__global__ __launch_bounds__(256, 2) void gabor_conv(
    const float* __restrict__ fp, const int* __restrict__ fmap,
    const int* __restrict__ tmap, const float2* __restrict__ tab,
    float* __restrict__ out)
{
    __shared__ float tile[NSTG];
    const int bh = blockIdx.y * PBY;
    const int bw = blockIdx.x * PBX;
    const int tid = threadIdx.x;

    for (int i = tid; i < NSTG; i += 256) {
        int r = i / TSTR, c = i - r * TSTR;
        int gr = bh + r, gc = bw + c;
        tile[i] = (gr < IMG && gc < IMG) ? fp[gr * IMG + gc] : 0.0f;
    }
    __syncthreads();

    const int wave = tid >> 6, lane = tid & 63;
    const int half = lane >> 5, l = lane & 31;
    const int lr = l & 15, lh = l >> 4;          // col-slot / row-parity
    const int pb  = wave * 2 + half;             // pixel 0..7 within block
    const int pxl = pb & 3, pyl = pb >> 2;
    const int oy = bh + pyl, ox = bw + pxl;
    const bool valid = (oy < NOUT) && (ox < NOUT);

    float acc0 = 0.0f, acc1 = 0.0f;
    if (valid) {
        const int iy = oy + PADV, ix = ox + PADV;
        const int theta = tmap[iy * IMG + ix];
        float f0 = 0.025f + 0.0015f * (float)fmap[iy * IMG + ix];
        asm volatile("" : "+v"(f0));             // force fmap load before pipeline

        // lane l, float4 index k = 32*i + l -> byte 512*i + 16*l
        unsigned long long a  =
            (unsigned long long)(tab + (size_t)theta * TABQ) + (size_t)l * 16;
        unsigned long long a2 = a + 4096;
        const float* tbase = &tile[(pyl + lh) * TSTR + pxl + 2 * lr];

        f32x4 g0a, g0b, g0c, g0d, g1a, g1b, g1c, g1d;
        f32x4 g2a, g2b, g2c, g2d, g3a, g3b, g3c, g3d;

#define ISSUE(R0,R1,R2,R3,A,O0,O1,O2,O3) asm volatile(                        \
        "global_load_dwordx4 %0, %4, off offset:" #O0 "\n\t"                  \
        "global_load_dwordx4 %1, %4, off offset:" #O1 "\n\t"                  \
        "global_load_dwordx4 %2, %4, off offset:" #O2 "\n\t"                  \
        "global_load_dwordx4 %3, %4, off offset:" #O3                         \
        : "=&v"(R0), "=&v"(R1), "=&v"(R2), "=&v"(R3) : "v"(A) : "memory")
#define WAITTIE(N,R0,R1,R2,R3)                                                \
        asm volatile("s_waitcnt vmcnt(" #N ")"                                \
            : "+v"(R0), "+v"(R1), "+v"(R2), "+v"(R3) :: "memory");            \
        __builtin_amdgcn_sched_barrier(0)
#define COMP(W, i) { const float* tr_ = tbase + 2 * (i) * TSTR;               \
        float w0_ = W.x * __builtin_amdgcn_cosf(f0 * W.y);                    \
        float w1_ = W.z * __builtin_amdgcn_cosf(f0 * W.w);                    \
        acc0 = fmaf(tr_[0], w0_, acc0); acc1 = fmaf(tr_[1], w1_, acc1); }

        ISSUE(g0a,g0b,g0c,g0d, a,  0,    512,  1024, 1536);
        ISSUE(g1a,g1b,g1c,g1d, a,  2048, 2560, 3072, 3584);
        WAITTIE(4, g0a,g0b,g0c,g0d);                 // G0 ready (G1 in flight)
        ISSUE(g2a,g2b,g2c,g2d, a2, 0,    512,  1024, 1536);
        COMP(g0a, 0) COMP(g0b, 1) COMP(g0c, 2) COMP(g0d, 3)
        __builtin_amdgcn_sched_barrier(0);
        WAITTIE(4, g1a,g1b,g1c,g1d);                 // G1 ready (G2 in flight)
        ISSUE(g3a,g3b,g3c,g3d, a2, 2048, 2560, 3072, 3584);
        COMP(g1a, 4) COMP(g1b, 5) COMP(g1c, 6) COMP(g1d, 7)
        __builtin_amdgcn_sched_barrier(0);
        WAITTIE(4, g2a,g2b,g2c,g2d);                 // G2 ready (G3 in flight)
        COMP(g2a, 8) COMP(g2b, 9) COMP(g2c, 10) COMP(g2d, 11)
        __builtin_amdgcn_sched_barrier(0);
        WAITTIE(0, g3a,g3b,g3c,g3d);                 // G3 ready
        COMP(g3a, 12) COMP(g3b, 13) COMP(g3c, 14) COMP(g3d, 15)
#undef COMP
#undef WAITTIE
#undef ISSUE
    }

    // reduce the 32 lanes of each half-wave
    float v = acc0 + acc1;
    v += __shfl_xor(v, 1, 64);
    v += __shfl_xor(v, 2, 64);
    v += __shfl_xor(v, 4, 64);
    v += __shfl_xor(v, 8, 64);
    v += __shfl_xor(v, 16, 64);

    if (valid && l == 0)
        out[(oy + PADV) * IMG + (ox + PADV)] = v;
}

// ---- stage 1: min/max over full image (inner from out, border from fp) ----
__global__ __launch_bounds__(256) void reduce_partials(
    const float* __restrict__ fp, const float* __restrict__ out,
    float2* __restrict__ part)
{
    __shared__ float smin[4], smax[4];
    float vmin = INFINITY, vmax = -INFINITY;
    for (int p = blockIdx.x * 256 + threadIdx.x; p < IMG * IMG; p += RBLK * 256) {
        int i = p / IMG, j = p - i * IMG;
        bool inner = (i >= PADV) && (i < PADV + NOUT) && (j >= PADV) && (j < PADV + NOUT);
        float v = inner ? out[p] : fp[p];
        vmin = fminf(vmin, v);
        vmax = fmaxf(vmax, v);
    }
    for (int off = 32; off; off >>= 1) {
        vmin = fminf(vmin, __shfl_down(vmin, off, 64));
        vmax = fmaxf(vmax, __shfl_down(vmax, off, 64));
    }
    const int wave = threadIdx.x >> 6;
    if ((threadIdx.x & 63) == 0) { smin[wave] = vmin; smax[wave] = vmax; }
    __syncthreads();
    if (threadIdx.x == 0) {
        vmin = fminf(fminf(smin[0], smin[1]), fminf(smin[2], smin[3]));
        vmax = fmaxf(fmaxf(smax[0], smax[1]), fmaxf(smax[2], smax[3]));
        part[blockIdx.x] = make_float2(vmin, vmax);
    }
}

// ---- stage 2: single block reduces RBLK partials -> mm (plain floats) ----
__global__ __launch_bounds__(RBLK) void reduce_final(
    const float2* __restrict__ part, float* __restrict__ mm)
{
    __shared__ float smin[2], smax[2];
    float2 v = part[threadIdx.x];
    float vmin = v.x, vmax = v.y;
    for (int off = 32; off; off >>= 1) {
        vmin = fminf(vmin, __shfl_down(vmin, off, 64));
        vmax = fmaxf(vmax, __shfl_down(vmax, off, 64));
    }
    const int wave = threadIdx.x >> 6;
    if ((threadIdx.x & 63) == 0) { smin[wave] = vmin; smax[wave] = vmax; }
    __syncthreads();
    if (threadIdx.x == 0) {
        mm[0] = fminf(smin[0], smin[1]);
        mm[1] = fmaxf(smax[0], smax[1]);
    }
}

// ---- finalize: normalize + threshold (border read from fp directly) ----
__global__ __launch_bounds__(256) void finalize(
    const float* __restrict__ fp, float* __restrict__ out,
    const float* __restrict__ mm)
{
    int p = blockIdx.x * 256 + threadIdx.x;
    if (p >= IMG * IMG) return;
    int i = p / IMG, j = p - i * IMG;
    bool inner = (i >= PADV) && (i < PADV + NOUT) && (j >= PADV) && (j < PADV + NOUT);
    float raw = inner ? out[p] : fp[p];
    float mn = mm[0];
    float mx = mm[1] - mn;               // max(out - min) == max0 - min0
    float v  = raw - mn;
    if (mx != 0.0f) v = v / mx * 100.0f;
    out[p] = (v > 55.0f) ? 100.0f : 0.0f;
}

extern "C" void kernel_launch(void* const* d_in, const int* in_sizes, int n_in,
                              void* d_out, int out_size, void* d_ws, size_t ws_size,
                              hipStream_t stream) {
    const float* fp   = (const float*)d_in[0];
    const int*   fmap = (const int*)d_in[1];
    const int*   tmap = (const int*)d_in[2];
    float* out = (float*)d_out;

    float*  mm   = (float*)d_ws;                          // 2 floats
    float2* part = (float2*)((char*)d_ws + 256);          // RBLK float2
    float2* tab  = (float2*)((char*)d_ws + 4096);         // 180*1024*8 = 1.47 MB

    hipLaunchKernelGGL(build_eftab, dim3(NTH * 4), dim3(256), 0, stream, tab);

    dim3 g((NOUT + PBX - 1) / PBX, (NOUT + PBY - 1) / PBY);   // 73 x 145
    hipLaunchKernelGGL(gabor_conv, g, dim3(256), 0, stream, fp, fmap, tmap, tab, out);

    hipLaunchKernelGGL(reduce_partials, dim3(RBLK), dim3(256), 0, stream, fp, out, part);
    hipLaunchKernelGGL(reduce_final,    dim3(1),    dim3(RBLK), 0, stream, part, mm);

    int nblk = (IMG * IMG + 255) / 256;
    hipLaunchKernelGGL(finalize, dim3(nblk), dim3(256), 0, stream, fp, out, mm);
}